// Round 8
// baseline (191.697 us; speedup 1.0000x reference)
//
#include <hip/hip_runtime.h>
#include <hip/hip_bf16.h>

#define NROWS 8192
#define KD    1024

typedef __attribute__((ext_vector_type(8))) short bf16x8;
typedef __attribute__((ext_vector_type(16))) float f32x16;

__device__ unsigned short g_x1n[(size_t)NROWS * KD];
__device__ unsigned short g_x2n[(size_t)NROWS * KD];

__device__ __forceinline__ unsigned short f2bf(float f) {
    union { float f; unsigned u; } x; x.f = f;
    return (unsigned short)((x.u + 0x7fffu + ((x.u >> 16) & 1u)) >> 16);  // RNE
}

__global__ __launch_bounds__(256) void norm_cast_kernel(const float* __restrict__ x1,
                                                        const float* __restrict__ x2) {
    int row = blockIdx.x;
    const float* src;
    unsigned short* dst;
    if (row < NROWS) { src = x1 + (size_t)row * KD;           dst = g_x1n + (size_t)row * KD; }
    else             { src = x2 + (size_t)(row - NROWS) * KD; dst = g_x2n + (size_t)(row - NROWS) * KD; }

    int t = threadIdx.x;
    float4 v = ((const float4*)src)[t];
    float s = v.x * v.x + v.y * v.y + v.z * v.z + v.w * v.w;
    #pragma unroll
    for (int off = 32; off > 0; off >>= 1) s += __shfl_down(s, off);

    __shared__ float red[4];
    if ((t & 63) == 0) red[t >> 6] = s;
    __syncthreads();
    float tot = red[0] + red[1] + red[2] + red[3];
    float inv = 1.0f / fmaxf(sqrtf(tot), 1e-8f);

    ushort4 o;
    o.x = f2bf(v.x * inv); o.y = f2bf(v.y * inv);
    o.z = f2bf(v.z * inv); o.w = f2bf(v.w * inv);
    ((ushort4*)dst)[t] = o;
}

__device__ __forceinline__ void gload_lds16(const unsigned short* g, unsigned short* l) {
    __builtin_amdgcn_global_load_lds((const __attribute__((address_space(1))) void*)g,
                                     (__attribute__((address_space(3))) void*)l,
                                     16, 0, 0);
}

#define BARX() do { asm volatile("" ::: "memory"); __builtin_amdgcn_s_barrier(); \
                    asm volatile("" ::: "memory"); } while (0)
#define DRAIN_LDS() do { asm volatile("s_waitcnt lgkmcnt(0)" ::: "memory"); \
                         __builtin_amdgcn_sched_barrier(0); } while (0)
#define MFMA32(a, b, c) __builtin_amdgcn_mfma_f32_32x32x16_bf16((a), (b), (c), 0, 0, 0)

struct Ctx {
    const unsigned short* Ablk;
    const unsigned short* Bblk;
    unsigned short* ldsf;
    int t;
    int trow;                     // t>>3 (staging row 0..63)
    int scol;                     // pre-swizzled source col element offset
    int abase;                    // r32*64
    int bbase;                    // (wc&1)*4096 + r32*64
    int soff[4];                  // swizzled 16B-slot offsets per kblk
    int wr, wch;
};

// Stage one half-tile (128 rows x 64 k): 2 x global_load_lds(16B) per thread.
// LDS dest LINEAR; global source carries the inverse swizzle (scol).
__device__ __forceinline__ void stage_half(const Ctx& c, const unsigned short* mat,
                                           int hbit, int region, int Tk) {
    const unsigned short* src = mat + (size_t)(hbit * 128 + c.trow) * KD + Tk * 64 + c.scol;
    unsigned short* dst = c.ldsf + region * 8192 + c.t * 8;
    gload_lds16(src, dst);
    gload_lds16(src + (size_t)64 * KD, dst + 4096);
}

// One K-tile (BK=64), 32x32x16 MFMA: 4 phases (C-quadrants), 8 MFMA each.
// Stage: q0 -> (T+1).A0, q1 -> (T+1).A1, q2 -> (T+2).B0, q3 -> (T+2).B1
template<int BUF, bool SA, bool SB, int WAITN>
__device__ __forceinline__ void tile_body(const Ctx& c, f32x16 (&acc)[4][2], int T) {
    const unsigned short* ab = c.ldsf + (BUF * 4 + c.wr) * 8192;
    const unsigned short* bb = c.ldsf + (BUF * 4 + 2 + c.wch) * 8192;
    bf16x8 Ar[2][4], Bl[4], Bh[4];

    // ---- q0: read A rb0-1 (8) + B cb0 (4); MFMA rb0-1 x cb0 ----
    #pragma unroll
    for (int k = 0; k < 4; ++k) {
        Ar[0][k] = *(const bf16x8*)(ab + 0 * 2048 + c.abase + c.soff[k]);
        Ar[1][k] = *(const bf16x8*)(ab + 1 * 2048 + c.abase + c.soff[k]);
        Bl[k]    = *(const bf16x8*)(bb + 0 * 2048 + c.bbase + c.soff[k]);
    }
    if (SA) stage_half(c, c.Ablk, 0, ((BUF ^ 1) * 4 + 0), T + 1);
    asm volatile("s_waitcnt lgkmcnt(8)" ::: "memory");   // 12-read phase pacing hint
    BARX();
    DRAIN_LDS();
    __builtin_amdgcn_s_setprio(1);
    #pragma unroll
    for (int k = 0; k < 4; ++k) {
        acc[0][0] = MFMA32(Ar[0][k], Bl[k], acc[0][0]);
        acc[1][0] = MFMA32(Ar[1][k], Bl[k], acc[1][0]);
    }
    __builtin_amdgcn_s_setprio(0);
    BARX();

    // ---- q1: read B cb1 (4); MFMA rb0-1 x cb1 ----
    #pragma unroll
    for (int k = 0; k < 4; ++k)
        Bh[k] = *(const bf16x8*)(bb + 1 * 2048 + c.bbase + c.soff[k]);
    if (SA) stage_half(c, c.Ablk, 1, ((BUF ^ 1) * 4 + 1), T + 1);
    BARX();
    DRAIN_LDS();
    __builtin_amdgcn_s_setprio(1);
    #pragma unroll
    for (int k = 0; k < 4; ++k) {
        acc[0][1] = MFMA32(Ar[0][k], Bh[k], acc[0][1]);
        acc[1][1] = MFMA32(Ar[1][k], Bh[k], acc[1][1]);
    }
    __builtin_amdgcn_s_setprio(0);
    BARX();

    // ---- q2: read A rb2-3 (8, overwrite Ar); MFMA rb2-3 x cb1 ----
    #pragma unroll
    for (int k = 0; k < 4; ++k) {
        Ar[0][k] = *(const bf16x8*)(ab + 2 * 2048 + c.abase + c.soff[k]);
        Ar[1][k] = *(const bf16x8*)(ab + 3 * 2048 + c.abase + c.soff[k]);
    }
    if (SB) stage_half(c, c.Bblk, 0, (BUF * 4 + 2), T + 2);
    BARX();
    DRAIN_LDS();
    __builtin_amdgcn_s_setprio(1);
    #pragma unroll
    for (int k = 0; k < 4; ++k) {
        acc[2][1] = MFMA32(Ar[0][k], Bh[k], acc[2][1]);
        acc[3][1] = MFMA32(Ar[1][k], Bh[k], acc[3][1]);
    }
    __builtin_amdgcn_s_setprio(0);
    BARX();

    // ---- q3: 0 reads; MFMA rb2-3 x cb0 ----
    if (SB) stage_half(c, c.Bblk, 1, (BUF * 4 + 3), T + 2);
    BARX();
    DRAIN_LDS();
    __builtin_amdgcn_s_setprio(1);
    #pragma unroll
    for (int k = 0; k < 4; ++k) {
        acc[2][0] = MFMA32(Ar[0][k], Bl[k], acc[2][0]);
        acc[3][0] = MFMA32(Ar[1][k], Bl[k], acc[3][0]);
    }
    __builtin_amdgcn_s_setprio(0);
    if (WAITN == 4)      asm volatile("s_waitcnt vmcnt(4)" ::: "memory");
    else if (WAITN == 0) asm volatile("s_waitcnt vmcnt(0)" ::: "memory");
    BARX();
}

// 256x256 tile, BK=64, 8 waves (2M x 4N), 32x32x16 MFMA, 8-phase counted-vmcnt.
__global__ __launch_bounds__(512, 2) void gemm8_kernel(float* __restrict__ C) {
    __shared__ unsigned short lds[2][4][8192];   // 128 KiB

    // L2-rectangle XCD mapping (bijective), bn-band pinned per XCD (round 5: FETCH -63%).
    int bid = blockIdx.x;                 // 1024 blocks
    int xcd  = bid & 7;
    int idx  = bid >> 3;
    int rnd  = idx >> 5;
    int j    = idx & 31;
    int rect = rnd * 8 + xcd;
    int bm = (rect >> 2) * 4 + (j >> 3);
    int bn = (rect & 3) * 8 + (j & 7);

    int t = threadIdx.x;
    int lane = t & 63, wid = t >> 6;
    int wr = wid >> 2, wc = wid & 3;
    int r32 = lane & 31;
    int kh  = lane >> 5;                  // k-half (0/1)

    Ctx c;
    c.Ablk = g_x1n + (size_t)bm * 256 * KD;
    c.Bblk = g_x2n + (size_t)bn * 256 * KD;
    c.ldsf = &lds[0][0][0];
    c.t = t;
    c.trow = t >> 3;
    c.scol = (((t & 7) ^ ((t >> 3) & 7))) * 8;   // inverse swizzle on global source
    c.abase = r32 * 64;
    c.bbase = (wc & 1) * 4096 + r32 * 64;
    #pragma unroll
    for (int k = 0; k < 4; ++k)
        c.soff[k] = ((k * 2 + kh) ^ (r32 & 7)) * 8;   // swizzled 16B slot
    c.wr = wr;
    c.wch = wc >> 1;

    f32x16 acc[4][2] = {};

    // Prologue: tile0 {B0,B1,A0,A1}, tile1 {B0,B1}; wait tile0 complete.
    stage_half(c, c.Bblk, 0, 2, 0);
    stage_half(c, c.Bblk, 1, 3, 0);
    stage_half(c, c.Ablk, 0, 0, 0);
    stage_half(c, c.Ablk, 1, 1, 0);
    stage_half(c, c.Bblk, 0, 6, 1);
    stage_half(c, c.Bblk, 1, 7, 1);
    asm volatile("s_waitcnt vmcnt(4)" ::: "memory");
    BARX();

    for (int it = 0; it < 7; ++it) {      // tiles 0..13, full staging
        tile_body<0, true, true, 4>(c, acc, 2 * it);
        tile_body<1, true, true, 4>(c, acc, 2 * it + 1);
    }
    tile_body<0, true, false, 0>(c, acc, 14);   // stages (15).A0/A1, drain
    tile_body<1, false, false, -1>(c, acc, 15);

    // Epilogue: 32x32 C/D layout (m74/m101): col = lane&31,
    // row = (reg&3) + 8*(reg>>2) + 4*(lane>>5).
    int rbase = bm * 256 + wr * 128;
    int cbase = bn * 256 + wc * 64 + r32;
    int rk = 4 * kh;
    #pragma unroll
    for (int rb = 0; rb < 4; ++rb)
        #pragma unroll
        for (int cb = 0; cb < 2; ++cb)
            #pragma unroll
            for (int reg = 0; reg < 16; ++reg) {
                int row = rbase + rb * 32 + (reg & 3) + 8 * (reg >> 2) + rk;
                C[(size_t)row * NROWS + cbase + cb * 32] = acc[rb][cb][reg] * 20.0f;
            }
}

extern "C" void kernel_launch(void* const* d_in, const int* in_sizes, int n_in,
                              void* d_out, int out_size, void* d_ws, size_t ws_size,
                              hipStream_t stream) {
    (void)in_sizes; (void)n_in; (void)d_ws; (void)ws_size; (void)out_size;
    const float* x1 = (const float*)d_in[0];
    const float* x2 = (const float*)d_in[1];
    float* out = (float*)d_out;

    norm_cast_kernel<<<2 * NROWS, 256, 0, stream>>>(x1, x2);
    gemm8_kernel<<<(NROWS / 256) * (NROWS / 256), 512, 0, stream>>>(out);
}